// Round 1
// 1325.890 us; speedup vs baseline: 1.2695x; 1.2695x over previous
//
#include <hip/hip_runtime.h>
#include <math.h>

#define DIM 1024
#define NSUB 1024
#define KEYD 256
#define CODED 128
#define NTOK 8192

typedef unsigned long long u64;

// ---------------- fp32 GEMM (NT): C[M,N] = A[M,K] * B[N,K]^T, optional silu
// 128x128 block tile, 256 threads, 8x8 micro-tile, float4 global loads.
// Double-buffered LDS: tile t+1's global loads are issued before tile t's
// compute so load latency hides under the 512-FMA block; one barrier/tile.
// Accumulation is STILL a single fp32 FMA chain in ascending k order per
// output (bit-identical to the previous kernel) — the reference's selection
// decisions depend on fp32 score rounding, so arithmetic must not change.
template<int SILU>
__global__ __launch_bounds__(256) void sgemm_nt(
    const float* __restrict__ A, const float* __restrict__ B, float* __restrict__ C,
    int M, int N, int K, int lda, int ldb, int ldc)
{
  __shared__ float As[2][8][128];
  __shared__ float Bs[2][8][128];
  const int tid = threadIdx.x;
  const int m0 = blockIdx.y * 128, n0 = blockIdx.x * 128;
  const int lrow = tid >> 1;        // 0..127
  const int lk   = (tid & 1) * 4;   // 0 or 4
  const int tx = tid & 15, ty = tid >> 4;
  float acc[8][8] = {{0.f}};
  const float* Ap = A + (size_t)(m0 + lrow) * lda + lk;
  const float* Bp = B + (size_t)(n0 + lrow) * ldb + lk;

  // prologue: stage tile 0 into buffer 0
  {
    float4 av = *(const float4*)(Ap);
    float4 bv = *(const float4*)(Bp);
    As[0][lk + 0][lrow] = av.x; As[0][lk + 1][lrow] = av.y;
    As[0][lk + 2][lrow] = av.z; As[0][lk + 3][lrow] = av.w;
    Bs[0][lk + 0][lrow] = bv.x; Bs[0][lk + 1][lrow] = bv.y;
    Bs[0][lk + 2][lrow] = bv.z; Bs[0][lk + 3][lrow] = bv.w;
  }
  __syncthreads();
  const int T = K >> 3;
  int cur = 0;
  for (int t = 0; t < T; ++t) {
    // issue next tile's global loads early (branchless: last iter reloads t)
    const int tn = (t + 1 < T) ? (t + 1) : t;
    float4 av = *(const float4*)(Ap + tn * 8);
    float4 bv = *(const float4*)(Bp + tn * 8);
#pragma unroll
    for (int k = 0; k < 8; ++k) {
      float a[8], b[8];
      *(float4*)&a[0] = *(const float4*)&As[cur][k][ty * 8];
      *(float4*)&a[4] = *(const float4*)&As[cur][k][ty * 8 + 4];
      *(float4*)&b[0] = *(const float4*)&Bs[cur][k][tx * 8];
      *(float4*)&b[4] = *(const float4*)&Bs[cur][k][tx * 8 + 4];
#pragma unroll
      for (int i = 0; i < 8; ++i)
#pragma unroll
        for (int j = 0; j < 8; ++j)
          acc[i][j] = fmaf(a[i], b[j], acc[i][j]);
    }
    // store next tile into the other buffer (readers of As[cur] are done
    // only after the barrier below, but we write As[cur^1] — disjoint).
    const int nx = cur ^ 1;
    As[nx][lk + 0][lrow] = av.x; As[nx][lk + 1][lrow] = av.y;
    As[nx][lk + 2][lrow] = av.z; As[nx][lk + 3][lrow] = av.w;
    Bs[nx][lk + 0][lrow] = bv.x; Bs[nx][lk + 1][lrow] = bv.y;
    Bs[nx][lk + 2][lrow] = bv.z; Bs[nx][lk + 3][lrow] = bv.w;
    __syncthreads();
    cur ^= 1;
  }
#pragma unroll
  for (int i = 0; i < 8; ++i) {
    float* Cp = C + (size_t)(m0 + ty * 8 + i) * ldc + n0 + tx * 8;
    float v[8];
#pragma unroll
    for (int j = 0; j < 8; ++j) {
      float z = acc[i][j];
      if (SILU) z = z / (1.0f + expf(-z));
      v[j] = z;
    }
    *(float4*)(Cp)     = *(float4*)&v[0];
    *(float4*)(Cp + 4) = *(float4*)&v[4];
  }
}

// ---------------- top-k + softmax + code gather ----------------------------
// Wave-per-token, all-register bitonic top-32 via cross-lane shuffles.
// Sort key (u64): bits 16..47 = monotone-mapped fp32 (lossless), bits 0..15 =
// (1023 - idx). Larger key = higher value, ties by LOWEST index — exactly
// jax.lax.top_k semantics on fp32 values (identical to previous kernel).
__device__ inline unsigned int fmap32(float f) {
  unsigned int u = __float_as_uint(f);
  return (u >> 31) ? ~u : (u | 0x80000000u);
}
__device__ inline float funmap32(unsigned int m) {
  return __uint_as_float((m & 0x80000000u) ? (m ^ 0x80000000u) : ~m);
}
__device__ inline u64 pack_key(float f, int e) {
  return ((u64)fmap32(f) << 16) | (u64)(1023 - e);
}
__device__ inline u64 shflx64(u64 v, int mask) {
  return __shfl_xor(v, mask, 64);
}
__device__ inline void cmpex(u64& x, u64 p, bool takeMax) {
  // takeMax -> x = max(x,p); else x = min(x,p). Keys are unique (index bits).
  if ((x < p) == takeMax) x = p;
}

// Sort each 32-lane half's values descending, NR registers simultaneously.
// Runtime size/stride loops (small code, I-cache friendly); reg loop unrolled
// so k[] stays in registers.
template<int NR>
__device__ inline void sort32_desc(u64* k, int l5) {
#pragma unroll 1
  for (int size = 2; size <= 32; size <<= 1) {
#pragma unroll 1
    for (int stride = size >> 1; stride > 0; stride >>= 1) {
      const bool takeMax = (((l5 & size) == 0) == ((l5 & stride) == 0));
#pragma unroll
      for (int r = 0; r < NR; ++r) {
        u64 p = shflx64(k[r], stride);
        cmpex(k[r], p, takeMax);
      }
    }
  }
}

// Clean a bitonic 32-sequence (per half-wave) to descending order.
template<int NR>
__device__ inline void bmerge32_desc(u64* k, int l5) {
#pragma unroll 1
  for (int stride = 16; stride > 0; stride >>= 1) {
    const bool takeMax = ((l5 & stride) == 0);
#pragma unroll
    for (int r = 0; r < NR; ++r) {
      u64 p = shflx64(k[r], stride);
      cmpex(k[r], p, takeMax);
    }
  }
}

// Each reg holds two desc-sorted 32-chunks (lanes 0-31 / 32-63). Produce the
// top-32 of the 64, sorted desc, replicated into both halves:
// max(A[i], B[31-i]) (via shfl_xor 63) is bitonic and contains exactly the
// top-32 multiset (first stage of the Batcher merge), then 5-step clean.
template<int NR>
__device__ inline void halfmerge(u64* k, int l5) {
#pragma unroll
  for (int r = 0; r < NR; ++r) {
    u64 p = shflx64(k[r], 63);
    if (k[r] < p) k[r] = p;
  }
  bmerge32_desc<NR>(k, l5);
}

// x, y: top-32 lists, desc-sorted, replicated in both halves. Returns the
// top-32 of x ∪ y, desc-sorted, replicated.
__device__ inline u64 merge2(u64 x, u64 y, int l5) {
  u64 p = shflx64(y, 31);     // y[31 - l5] within each half
  if (x < p) x = p;           // bitonic top-32 of the pair
  bmerge32_desc<1>(&x, l5);
  return x;
}

// 1024 elements as 16 regs/lane -> top-32 desc, replicated in both halves.
__device__ inline u64 top32_of_1024(u64 k[16], int l5) {
  sort32_desc<16>(k, l5);     // 32 chunks of 32, each sorted desc
  halfmerge<16>(k, l5);       // 16 replicated top-32-of-64 lists
#pragma unroll
  for (int r = 0; r < 8; ++r) k[r] = merge2(k[2 * r], k[2 * r + 1], l5);
#pragma unroll
  for (int r = 0; r < 4; ++r) k[r] = merge2(k[2 * r], k[2 * r + 1], l5);
#pragma unroll
  for (int r = 0; r < 2; ++r) k[r] = merge2(k[2 * r], k[2 * r + 1], l5);
  return merge2(k[0], k[1], l5);
}

__global__ __launch_bounds__(256) void topk_mix(
    const float* __restrict__ scores,    // [NTOK][2048] (a: 0..1023, b: 1024..2047)
    const float* __restrict__ codes,     // [NSUB*NSUB][CODED]
    float* __restrict__ mixed)           // [NTOK][CODED]
{
  const int lane = threadIdx.x & 63;
  const int wid  = threadIdx.x >> 6;
  const int token = blockIdx.x * 4 + wid;   // 4 independent waves per block
  const int l5 = lane & 31;
  const int hi = lane >> 5;
  const float* row = scores + (size_t)token * 2048;

  u64 k[16];

  // ---- top-32 of scores_a (fp32 values, jax tie-break) ----
#pragma unroll
  for (int r4 = 0; r4 < 4; ++r4) {
    float4 v = *(const float4*)(row + r4 * 256 + 4 * lane);
    const int e = r4 * 256 + 4 * lane;
    k[4 * r4 + 0] = pack_key(v.x, e + 0);
    k[4 * r4 + 1] = pack_key(v.y, e + 1);
    k[4 * r4 + 2] = pack_key(v.z, e + 2);
    k[4 * r4 + 3] = pack_key(v.w, e + 3);
  }
  const u64 ka = top32_of_1024(k, l5);
  const float va = funmap32((unsigned int)(ka >> 16));  // lossless value recovery
  const int   ia = 1023 - (int)(ka & 0xFFFFULL);

  // ---- top-32 of scores_b ----
#pragma unroll
  for (int r4 = 0; r4 < 4; ++r4) {
    float4 v = *(const float4*)(row + 1024 + r4 * 256 + 4 * lane);
    const int e = r4 * 256 + 4 * lane;
    k[4 * r4 + 0] = pack_key(v.x, e + 0);
    k[4 * r4 + 1] = pack_key(v.y, e + 1);
    k[4 * r4 + 2] = pack_key(v.z, e + 2);
    k[4 * r4 + 3] = pack_key(v.w, e + 3);
  }
  const u64 kb = top32_of_1024(k, l5);
  const float vb = funmap32((unsigned int)(kb >> 16));
  const int   ib = 1023 - (int)(kb & 0xFFFFULL);

  // ---- top-32 of the 1024 candidate sums ----
  // p = ra*32 + rb with ra = 2r + hi (uniform per reg/half), rb = l5.
  // value = ta_s[ra] + tb_s[rb]: single fp32 add — matches ref bit-exactly.
#pragma unroll
  for (int r = 0; r < 16; ++r) {
    const float ta = __shfl(va, 2 * r + hi, 64);
    const float s  = ta + vb;            // tb_s[rb] is this lane's own vb
    const int   p  = r * 64 + lane;      // == (2r+hi)*32 + l5
    k[r] = pack_key(s, p);
  }
  const u64 kc = top32_of_1024(k, l5);
  const float cs = funmap32((unsigned int)(kc >> 16));
  const int   ps = 1023 - (int)(kc & 0xFFFFULL);
  const int cidx = __shfl(ia, ps >> 5, 64) * NSUB + __shfl(ib, ps & 31, 64);

  // ---- fp32 softmax over the 32 selected; rank 0 (lane 0) is the max ----
  const float lg  = cs / 22.627416997969522f;
  const float lg0 = __shfl(lg, 0, 64);
  const float ev  = expf(lg - lg0);
  float s = ev;
#pragma unroll
  for (int m = 1; m < 32; m <<= 1) s += __shfl_xor(s, m, 64);
  const float w = ev / s;

  // ---- mixed[c] = sum_k w_k * codes[idx_k][c]; lane covers c = 2*lane,+1 ----
  float2 acc = make_float2(0.f, 0.f);
#pragma unroll 8
  for (int kk = 0; kk < 32; ++kk) {
    const int   idx = __shfl(cidx, kk, 64);
    const float wk  = __shfl(w,    kk, 64);
    const float2 cv = *(const float2*)(codes + (size_t)idx * CODED + 2 * lane);
    acc.x = fmaf(wk, cv.x, acc.x);
    acc.y = fmaf(wk, cv.y, acc.y);
  }
  *(float2*)(mixed + (size_t)token * CODED + 2 * lane) = acc;
}

extern "C" void kernel_launch(void* const* d_in, const int* in_sizes, int n_in,
                              void* d_out, int out_size, void* d_ws, size_t ws_size,
                              hipStream_t stream)
{
  const float* x     = (const float*)d_in[0];
  const float* Wq    = (const float*)d_in[1];
  const float* key_a = (const float*)d_in[2];
  const float* key_b = (const float*)d_in[3];
  const float* codes = (const float*)d_in[4];
  const float* W1    = (const float*)d_in[5];
  const float* W2    = (const float*)d_in[6];
  float* out = (float*)d_out;

  // ws layout: q f32 [0,16MB), scores f32 [16,80MB), mixed [80,84MB),
  // h f32 [84,116MB)
  char* ws = (char*)d_ws;
  float* q      = (float*)(ws);
  float* scores = (float*)(ws + (size_t)16 * 1024 * 1024);
  float* mixed  = (float*)(ws + (size_t)80 * 1024 * 1024);
  float* h      = (float*)(ws + (size_t)84 * 1024 * 1024);

  // q = x @ Wq^T  (fp32, sequential-k accumulation like the reference)
  sgemm_nt<0><<<dim3(512 / 128, NTOK / 128), 256, 0, stream>>>(
      x, Wq, q, NTOK, 512, DIM, DIM, DIM, 512);
  // scores_a = q[:, :256] @ key_a^T ; scores_b = q[:, 256:] @ key_b^T
  sgemm_nt<0><<<dim3(NSUB / 128, NTOK / 128), 256, 0, stream>>>(
      q, key_a, scores, NTOK, NSUB, KEYD, 512, KEYD, 2048);
  sgemm_nt<0><<<dim3(NSUB / 128, NTOK / 128), 256, 0, stream>>>(
      q + KEYD, key_b, scores + NSUB, NTOK, NSUB, KEYD, 512, KEYD, 2048);
  // per-token product-key top-k -> softmax -> code mix (all fp32, in-register)
  topk_mix<<<NTOK / 4, 256, 0, stream>>>(scores, codes, mixed);
  // h = silu(mixed @ W1^T)
  sgemm_nt<1><<<dim3(DIM / 128, NTOK / 128), 256, 0, stream>>>(
      mixed, W1, h, NTOK, DIM, CODED, CODED, CODED, DIM);
  // out = h @ W2^T
  sgemm_nt<0><<<dim3(DIM / 128, NTOK / 128), 256, 0, stream>>>(
      h, W2, out, NTOK, DIM, DIM, DIM, DIM, DIM);
}

// Round 3
// 1255.158 us; speedup vs baseline: 1.3410x; 1.0564x over previous
//
#include <hip/hip_runtime.h>
#include <math.h>

#define DIM 1024
#define NSUB 1024
#define KEYD 256
#define CODED 128
#define NTOK 8192

typedef unsigned long long u64;

// ---------------- fp32 GEMM (NT): C[M,N] = A[M,K] * B[N,K]^T, optional silu
// 128x128 block tile, 256 threads, 8x8 micro-tile, float4 global loads.
// Double-buffered LDS. Micro-tile columns are SPLIT (tx*4 and 64+tx*4) so the
// Bs ds_read_b128 hits 16 addresses at 16B stride = 2-way bank aliasing
// (free) instead of the 32B-stride 4-way conflict of a contiguous tx*8 span.
// Accumulation is STILL a single fp32 FMA chain in ascending k order per
// output (bit-identical) — the reference's selection depends on fp32 score
// rounding, so per-element arithmetic must not change.
template<int SILU>
__global__ __launch_bounds__(256) void sgemm_nt(
    const float* __restrict__ A, const float* __restrict__ B, float* __restrict__ C,
    int M, int N, int K, int lda, int ldb, int ldc)
{
  __shared__ float As[2][8][128];
  __shared__ float Bs[2][8][128];
  const int tid = threadIdx.x;
  const int m0 = blockIdx.y * 128, n0 = blockIdx.x * 128;
  const int lrow = tid >> 1;        // 0..127
  const int lk   = (tid & 1) * 4;   // 0 or 4
  const int tx = tid & 15, ty = tid >> 4;
  float acc[8][8] = {{0.f}};
  const float* Ap = A + (size_t)(m0 + lrow) * lda + lk;
  const float* Bp = B + (size_t)(n0 + lrow) * ldb + lk;

  // prologue: stage tile 0 into buffer 0
  {
    float4 av = *(const float4*)(Ap);
    float4 bv = *(const float4*)(Bp);
    As[0][lk + 0][lrow] = av.x; As[0][lk + 1][lrow] = av.y;
    As[0][lk + 2][lrow] = av.z; As[0][lk + 3][lrow] = av.w;
    Bs[0][lk + 0][lrow] = bv.x; Bs[0][lk + 1][lrow] = bv.y;
    Bs[0][lk + 2][lrow] = bv.z; Bs[0][lk + 3][lrow] = bv.w;
  }
  __syncthreads();
  const int T = K >> 3;
  int cur = 0;
  for (int t = 0; t < T; ++t) {
    // issue next tile's global loads early (branchless: last iter reloads t)
    const int tn = (t + 1 < T) ? (t + 1) : t;
    float4 av = *(const float4*)(Ap + tn * 8);
    float4 bv = *(const float4*)(Bp + tn * 8);
#pragma unroll
    for (int k = 0; k < 8; ++k) {
      float a[8], b[8];
      *(float4*)&a[0] = *(const float4*)&As[cur][k][ty * 8];
      *(float4*)&a[4] = *(const float4*)&As[cur][k][ty * 8 + 4];
      *(float4*)&b[0] = *(const float4*)&Bs[cur][k][tx * 4];
      *(float4*)&b[4] = *(const float4*)&Bs[cur][k][64 + tx * 4];
#pragma unroll
      for (int i = 0; i < 8; ++i)
#pragma unroll
        for (int j = 0; j < 8; ++j)
          acc[i][j] = fmaf(a[i], b[j], acc[i][j]);
    }
    // store next tile into the other buffer (disjoint from current readers)
    const int nx = cur ^ 1;
    As[nx][lk + 0][lrow] = av.x; As[nx][lk + 1][lrow] = av.y;
    As[nx][lk + 2][lrow] = av.z; As[nx][lk + 3][lrow] = av.w;
    Bs[nx][lk + 0][lrow] = bv.x; Bs[nx][lk + 1][lrow] = bv.y;
    Bs[nx][lk + 2][lrow] = bv.z; Bs[nx][lk + 3][lrow] = bv.w;
    __syncthreads();
    cur ^= 1;
  }
  // epilogue: thread owns rows ty*8+i, cols {tx*4..+3} and {64+tx*4..+3}
#pragma unroll
  for (int i = 0; i < 8; ++i) {
    float* Cp = C + (size_t)(m0 + ty * 8 + i) * ldc + n0;
    float v[8];
#pragma unroll
    for (int j = 0; j < 8; ++j) {
      float z = acc[i][j];
      if (SILU) z = z / (1.0f + expf(-z));
      v[j] = z;
    }
    *(float4*)(Cp + tx * 4)      = *(float4*)&v[0];
    *(float4*)(Cp + 64 + tx * 4) = *(float4*)&v[4];
  }
}

// ---------------- top-k + softmax + code gather ----------------------------
// Wave-per-token, all-register bitonic top-32 via cross-lane shuffles.
// Sort key (u64): bits 16..47 = monotone-mapped fp32 (lossless), bits 0..15 =
// (1023 - idx). Larger key = higher value, ties by LOWEST index — exactly
// jax.lax.top_k semantics on fp32 values.
__device__ inline unsigned int fmap32(float f) {
  unsigned int u = __float_as_uint(f);
  return (u >> 31) ? ~u : (u | 0x80000000u);
}
__device__ inline float funmap32(unsigned int m) {
  return __uint_as_float((m & 0x80000000u) ? (m ^ 0x80000000u) : ~m);
}
__device__ inline u64 pack_key(float f, int e) {
  return ((u64)fmap32(f) << 16) | (u64)(1023 - e);
}
__device__ inline u64 shflx64(u64 v, int mask) {
  return __shfl_xor(v, mask, 64);
}
__device__ inline void cmpex(u64& x, u64 p, bool takeMax) {
  // takeMax -> x = max(x,p); else x = min(x,p). Keys are unique (index bits).
  if ((x < p) == takeMax) x = p;
}

// Sort each 32-lane half's values descending, NR registers simultaneously.
template<int NR>
__device__ inline void sort32_desc(u64* k, int l5) {
#pragma unroll 1
  for (int size = 2; size <= 32; size <<= 1) {
#pragma unroll 1
    for (int stride = size >> 1; stride > 0; stride >>= 1) {
      const bool takeMax = (((l5 & size) == 0) == ((l5 & stride) == 0));
#pragma unroll
      for (int r = 0; r < NR; ++r) {
        u64 p = shflx64(k[r], stride);
        cmpex(k[r], p, takeMax);
      }
    }
  }
}

// Clean a bitonic 32-sequence (per half-wave) to descending order.
template<int NR>
__device__ inline void bmerge32_desc(u64* k, int l5) {
#pragma unroll 1
  for (int stride = 16; stride > 0; stride >>= 1) {
    const bool takeMax = ((l5 & stride) == 0);
#pragma unroll
    for (int r = 0; r < NR; ++r) {
      u64 p = shflx64(k[r], stride);
      cmpex(k[r], p, takeMax);
    }
  }
}

// Each reg holds two desc-sorted 32-chunks (lanes 0-31 / 32-63). Produce the
// top-32 of the 64, sorted desc, replicated into both halves.
template<int NR>
__device__ inline void halfmerge(u64* k, int l5) {
#pragma unroll
  for (int r = 0; r < NR; ++r) {
    u64 p = shflx64(k[r], 63);
    if (k[r] < p) k[r] = p;
  }
  bmerge32_desc<NR>(k, l5);
}

// x, y: top-32 lists, desc-sorted, replicated in both halves. Returns the
// top-32 of x ∪ y, desc-sorted, replicated.
__device__ inline u64 merge2(u64 x, u64 y, int l5) {
  u64 p = shflx64(y, 31);     // y[31 - l5] within each half
  if (x < p) x = p;           // bitonic top-32 of the pair
  bmerge32_desc<1>(&x, l5);
  return x;
}

// 1024 elements as 16 regs/lane -> top-32 desc, replicated in both halves.
__device__ inline u64 top32_of_1024(u64 k[16], int l5) {
  sort32_desc<16>(k, l5);     // 32 chunks of 32, each sorted desc
  halfmerge<16>(k, l5);       // 16 replicated top-32-of-64 lists
#pragma unroll
  for (int r = 0; r < 8; ++r) k[r] = merge2(k[2 * r], k[2 * r + 1], l5);
#pragma unroll
  for (int r = 0; r < 4; ++r) k[r] = merge2(k[2 * r], k[2 * r + 1], l5);
#pragma unroll
  for (int r = 0; r < 2; ++r) k[r] = merge2(k[2 * r], k[2 * r + 1], l5);
  return merge2(k[0], k[1], l5);
}

// Candidate-prune table: the top-32 of {ta[i]+tb[j]} (ta,tb desc-sorted) can
// only come from the staircase (i+1)*(j+1) <= 32 (fp32 add is monotone, and
// any dominated (i,j) loses ties by position too since i'<=i, j'<=j => p'<p).
// 119 real slots (p = i*32+j) + 9 pad sentinels (0xFFFF -> key 0).
__device__ const unsigned short cand_tab[128] = {
  // i=0: j=0..31
    0,  1,  2,  3,  4,  5,  6,  7,  8,  9, 10, 11, 12, 13, 14, 15,
   16, 17, 18, 19, 20, 21, 22, 23, 24, 25, 26, 27, 28, 29, 30, 31,
  // i=1: j=0..15
   32, 33, 34, 35, 36, 37, 38, 39, 40, 41, 42, 43, 44, 45, 46, 47,
  // i=2: j=0..9
   64, 65, 66, 67, 68, 69, 70, 71, 72, 73,
  // i=3: j=0..7
   96, 97, 98, 99,100,101,102,103,
  // i=4: j=0..5
  128,129,130,131,132,133,
  // i=5: j=0..4
  160,161,162,163,164,
  // i=6: j=0..3
  192,193,194,195,
  // i=7: j=0..3
  224,225,226,227,
  // i=8: j=0..2
  256,257,258,
  // i=9: j=0..2
  288,289,290,
  // i=10..15: j=0..1
  320,321, 352,353, 384,385, 416,417, 448,449, 480,481,
  // i=16..31: j=0
  512,544,576,608,640,672,704,736,768,800,832,864,896,928,960,992,
  // pad
  0xFFFF,0xFFFF,0xFFFF,0xFFFF,0xFFFF,0xFFFF,0xFFFF,0xFFFF,0xFFFF
};

__global__ __launch_bounds__(256) void topk_mix(
    const float* __restrict__ scores,    // [NTOK][2048] (a: 0..1023, b: 1024..2047)
    const float* __restrict__ codes,     // [NSUB*NSUB][CODED]
    float* __restrict__ mixed)           // [NTOK][CODED]
{
  const int lane = threadIdx.x & 63;
  const int wid  = threadIdx.x >> 6;
  const int token = blockIdx.x * 4 + wid;   // 4 independent waves per block
  const int l5 = lane & 31;
  const float* row = scores + (size_t)token * 2048;

  u64 k[16];

  // ---- top-32 of scores_a (fp32 values, jax tie-break) ----
#pragma unroll
  for (int r4 = 0; r4 < 4; ++r4) {
    float4 v = *(const float4*)(row + r4 * 256 + 4 * lane);
    const int e = r4 * 256 + 4 * lane;
    k[4 * r4 + 0] = pack_key(v.x, e + 0);
    k[4 * r4 + 1] = pack_key(v.y, e + 1);
    k[4 * r4 + 2] = pack_key(v.z, e + 2);
    k[4 * r4 + 3] = pack_key(v.w, e + 3);
  }
  const u64 ka = top32_of_1024(k, l5);
  const float va = funmap32((unsigned int)(ka >> 16));  // lossless value recovery
  const int   ia = 1023 - (int)(ka & 0xFFFFULL);

  // ---- top-32 of scores_b ----
#pragma unroll
  for (int r4 = 0; r4 < 4; ++r4) {
    float4 v = *(const float4*)(row + 1024 + r4 * 256 + 4 * lane);
    const int e = r4 * 256 + 4 * lane;
    k[4 * r4 + 0] = pack_key(v.x, e + 0);
    k[4 * r4 + 1] = pack_key(v.y, e + 1);
    k[4 * r4 + 2] = pack_key(v.z, e + 2);
    k[4 * r4 + 3] = pack_key(v.w, e + 3);
  }
  const u64 kb = top32_of_1024(k, l5);
  const float vb = funmap32((unsigned int)(kb >> 16));
  const int   ib = 1023 - (int)(kb & 0xFFFFULL);

  // ---- top-32 of candidate sums, pruned to the 119-slot staircase ----
  // value = ta[i] + tb[j]: single fp32 add — matches the reference bit-exactly.
#pragma unroll
  for (int r = 0; r < 2; ++r) {
    const int p  = cand_tab[r * 64 + lane];
    const int pi = (p == 0xFFFF) ? 0 : p;
    const float ta = __shfl(va, pi >> 5, 64);   // rank (pi>>5) value (replicated)
    const float tb = __shfl(vb, pi & 31, 64);   // rank (pi&31) value
    k[r] = (p == 0xFFFF) ? 0ULL : pack_key(ta + tb, p);
  }
  sort32_desc<2>(k, l5);
  halfmerge<2>(k, l5);
  const u64 kc = merge2(k[0], k[1], l5);
  const float cs = funmap32((unsigned int)(kc >> 16));
  const int   ps = 1023 - (int)(kc & 0xFFFFULL);
  const int cidx = __shfl(ia, ps >> 5, 64) * NSUB + __shfl(ib, ps & 31, 64);

  // ---- fp32 softmax over the 32 selected; rank 0 (lane 0) is the max ----
  const float lg  = cs / 22.627416997969522f;
  const float lg0 = __shfl(lg, 0, 64);
  const float ev  = expf(lg - lg0);
  float s = ev;
#pragma unroll
  for (int m = 1; m < 32; m <<= 1) s += __shfl_xor(s, m, 64);
  const float w = ev / s;

  // ---- mixed[c] = sum_k w_k * codes[idx_k][c]; lane covers c = 2*lane,+1 ----
  float2 acc = make_float2(0.f, 0.f);
#pragma unroll 8
  for (int kk = 0; kk < 32; ++kk) {
    const int   idx = __shfl(cidx, kk, 64);
    const float wk  = __shfl(w,    kk, 64);
    const float2 cv = *(const float2*)(codes + (size_t)idx * CODED + 2 * lane);
    acc.x = fmaf(wk, cv.x, acc.x);
    acc.y = fmaf(wk, cv.y, acc.y);
  }
  *(float2*)(mixed + (size_t)token * CODED + 2 * lane) = acc;
}

extern "C" void kernel_launch(void* const* d_in, const int* in_sizes, int n_in,
                              void* d_out, int out_size, void* d_ws, size_t ws_size,
                              hipStream_t stream)
{
  const float* x     = (const float*)d_in[0];
  const float* Wq    = (const float*)d_in[1];
  const float* key_a = (const float*)d_in[2];
  const float* key_b = (const float*)d_in[3];
  const float* codes = (const float*)d_in[4];
  const float* W1    = (const float*)d_in[5];
  const float* W2    = (const float*)d_in[6];
  float* out = (float*)d_out;

  // ws layout: q f32 [0,16MB), scores f32 [16,80MB), mixed [80,84MB),
  // h f32 [84,116MB)
  char* ws = (char*)d_ws;
  float* q      = (float*)(ws);
  float* scores = (float*)(ws + (size_t)16 * 1024 * 1024);
  float* mixed  = (float*)(ws + (size_t)80 * 1024 * 1024);
  float* h      = (float*)(ws + (size_t)84 * 1024 * 1024);

  // q = x @ Wq^T  (fp32, sequential-k accumulation like the reference)
  sgemm_nt<0><<<dim3(512 / 128, NTOK / 128), 256, 0, stream>>>(
      x, Wq, q, NTOK, 512, DIM, DIM, DIM, 512);
  // scores_a = q[:, :256] @ key_a^T ; scores_b = q[:, 256:] @ key_b^T
  sgemm_nt<0><<<dim3(NSUB / 128, NTOK / 128), 256, 0, stream>>>(
      q, key_a, scores, NTOK, NSUB, KEYD, 512, KEYD, 2048);
  sgemm_nt<0><<<dim3(NSUB / 128, NTOK / 128), 256, 0, stream>>>(
      q + KEYD, key_b, scores + NSUB, NTOK, NSUB, KEYD, 512, KEYD, 2048);
  // per-token product-key top-k -> softmax -> code mix (all fp32, in-register)
  topk_mix<<<NTOK / 4, 256, 0, stream>>>(scores, codes, mixed);
  // h = silu(mixed @ W1^T)
  sgemm_nt<1><<<dim3(DIM / 128, NTOK / 128), 256, 0, stream>>>(
      mixed, W1, h, NTOK, DIM, CODED, CODED, CODED, DIM);
  // out = h @ W2^T
  sgemm_nt<0><<<dim3(DIM / 128, NTOK / 128), 256, 0, stream>>>(
      h, W2, out, NTOK, DIM, DIM, DIM, DIM, DIM);
}

// Round 4
// 1097.539 us; speedup vs baseline: 1.5336x; 1.1436x over previous
//
#include <hip/hip_runtime.h>
#include <math.h>

#define DIM 1024
#define NSUB 1024
#define KEYD 256
#define CODED 128
#define NTOK 8192

typedef unsigned long long u64;
typedef __attribute__((ext_vector_type(8))) short short8;
typedef __attribute__((ext_vector_type(4))) float f32x4;

// ---------------- fp32 GEMM (NT): C[M,N] = A[M,K] * B[N,K]^T ---------------
// Used ONLY for the selection-critical GEMMs (q, scores_a, scores_b): their
// fp32 rounding determines top-k decisions, so accumulation stays a single
// fp32 FMA chain in ascending k order per output (bit-identical across
// rounds). 128x128 tile, 256 threads, 8x8 micro-tile, double-buffered LDS.
template<int SILU>
__global__ __launch_bounds__(256) void sgemm_nt(
    const float* __restrict__ A, const float* __restrict__ B, float* __restrict__ C,
    int M, int N, int K, int lda, int ldb, int ldc)
{
  __shared__ float As[2][8][128];
  __shared__ float Bs[2][8][128];
  const int tid = threadIdx.x;
  const int m0 = blockIdx.y * 128, n0 = blockIdx.x * 128;
  const int lrow = tid >> 1;        // 0..127
  const int lk   = (tid & 1) * 4;   // 0 or 4
  const int tx = tid & 15, ty = tid >> 4;
  float acc[8][8] = {{0.f}};
  const float* Ap = A + (size_t)(m0 + lrow) * lda + lk;
  const float* Bp = B + (size_t)(n0 + lrow) * ldb + lk;

  {
    float4 av = *(const float4*)(Ap);
    float4 bv = *(const float4*)(Bp);
    As[0][lk + 0][lrow] = av.x; As[0][lk + 1][lrow] = av.y;
    As[0][lk + 2][lrow] = av.z; As[0][lk + 3][lrow] = av.w;
    Bs[0][lk + 0][lrow] = bv.x; Bs[0][lk + 1][lrow] = bv.y;
    Bs[0][lk + 2][lrow] = bv.z; Bs[0][lk + 3][lrow] = bv.w;
  }
  __syncthreads();
  const int T = K >> 3;
  int cur = 0;
  for (int t = 0; t < T; ++t) {
    const int tn = (t + 1 < T) ? (t + 1) : t;
    float4 av = *(const float4*)(Ap + tn * 8);
    float4 bv = *(const float4*)(Bp + tn * 8);
#pragma unroll
    for (int k = 0; k < 8; ++k) {
      float a[8], b[8];
      *(float4*)&a[0] = *(const float4*)&As[cur][k][ty * 8];
      *(float4*)&a[4] = *(const float4*)&As[cur][k][ty * 8 + 4];
      *(float4*)&b[0] = *(const float4*)&Bs[cur][k][tx * 4];
      *(float4*)&b[4] = *(const float4*)&Bs[cur][k][64 + tx * 4];
#pragma unroll
      for (int i = 0; i < 8; ++i)
#pragma unroll
        for (int j = 0; j < 8; ++j)
          acc[i][j] = fmaf(a[i], b[j], acc[i][j]);
    }
    const int nx = cur ^ 1;
    As[nx][lk + 0][lrow] = av.x; As[nx][lk + 1][lrow] = av.y;
    As[nx][lk + 2][lrow] = av.z; As[nx][lk + 3][lrow] = av.w;
    Bs[nx][lk + 0][lrow] = bv.x; Bs[nx][lk + 1][lrow] = bv.y;
    Bs[nx][lk + 2][lrow] = bv.z; Bs[nx][lk + 3][lrow] = bv.w;
    __syncthreads();
    cur ^= 1;
  }
#pragma unroll
  for (int i = 0; i < 8; ++i) {
    float* Cp = C + (size_t)(m0 + ty * 8 + i) * ldc + n0;
    float v[8];
#pragma unroll
    for (int j = 0; j < 8; ++j) {
      float z = acc[i][j];
      if (SILU) z = z / (1.0f + expf(-z));
      v[j] = z;
    }
    *(float4*)(Cp + tx * 4)      = *(float4*)&v[0];
    *(float4*)(Cp + 64 + tx * 4) = *(float4*)&v[4];
  }
}

// ---------------- bf16 split helpers ---------------------------------------
// x = hi + lo with hi = bf16_rne(x), lo = bf16_rne(x - hi): ~16 mantissa
// bits. Product error ~2^-16 relative — post-selection GEMMs only.
__device__ inline unsigned bf16rne(float x) {
  unsigned u = __float_as_uint(x);
  return (u + 0x7FFFu + ((u >> 16) & 1u)) >> 16;
}

__global__ __launch_bounds__(256) void split_bf16(
    const float* __restrict__ w, unsigned short* __restrict__ hi,
    unsigned short* __restrict__ lo, int n)
{
  int i = blockIdx.x * 256 + threadIdx.x;
  if (i >= n) return;
  float x = w[i];
  unsigned h = bf16rne(x);
  float hf = __uint_as_float(h << 16);
  unsigned l = bf16rne(x - hf);
  hi[i] = (unsigned short)h;
  lo[i] = (unsigned short)l;
}

// ---------------- split-bf16 MFMA GEMM (NT): C = A * B^T -------------------
// A,B given as (hi,lo) bf16 pairs; C = Ahi*Bhi + Ahi*Blo + Alo*Bhi in fp32
// AGPRs. 128x128 tile, BK=32, 4 waves, each wave 64x64 = 4x4 fragments of
// mfma_f32_16x16x32_bf16. LDS rows padded to 40 elems (5 x 16B slots) so the
// per-fragment ds_read_b128 (stride 80B = 5 slots) covers all 8 bank-quads.
// Fragment layout: A/B lane l supplies row/col (l&15), k = (l>>4)*8+j;
// C/D: col = lane&15, row = (lane>>4)*4 + reg  [guide §3, m89-verified].
template<int SILU, int OSPLIT>
__global__ __launch_bounds__(256) void mgemm_nt(
    const unsigned short* __restrict__ Ahi, const unsigned short* __restrict__ Alo,
    const unsigned short* __restrict__ Bhi, const unsigned short* __restrict__ Blo,
    float* __restrict__ Cf, unsigned short* __restrict__ Chi,
    unsigned short* __restrict__ Clo, int M, int N, int K)
{
  __shared__ unsigned short Ah[128 * 40], Al[128 * 40], Bh[128 * 40], Bl[128 * 40];
  const int tid = threadIdx.x;
  const int m0 = blockIdx.y * 128, n0 = blockIdx.x * 128;
  const int lane = tid & 63, wv = tid >> 6;
  const int wm = (wv >> 1) * 64, wn = (wv & 1) * 64;   // wave's 64x64 origin
  const int l15 = lane & 15, l4 = lane >> 4;
  // staging: 512 chunks of 8 bf16 per array; thread handles chunks 2t, 2t+1
  const int c0 = tid * 2, c1 = tid * 2 + 1;
  const int r0 = c0 >> 2, g0 = c0 & 3, r1 = c1 >> 2, g1 = c1 & 3;

  f32x4 acc[4][4];
#pragma unroll
  for (int i = 0; i < 4; ++i)
#pragma unroll
    for (int j = 0; j < 4; ++j)
      acc[i][j] = (f32x4){0.f, 0.f, 0.f, 0.f};

  for (int kt = 0; kt < K; kt += 32) {
    __syncthreads();   // previous tile's reads complete before overwrite
    {
      const size_t a0 = (size_t)(m0 + r0) * K + kt + g0 * 8;
      const size_t a1 = (size_t)(m0 + r1) * K + kt + g1 * 8;
      const size_t b0 = (size_t)(n0 + r0) * K + kt + g0 * 8;
      const size_t b1 = (size_t)(n0 + r1) * K + kt + g1 * 8;
      *(uint4*)&Ah[r0 * 40 + g0 * 8] = *(const uint4*)(Ahi + a0);
      *(uint4*)&Ah[r1 * 40 + g1 * 8] = *(const uint4*)(Ahi + a1);
      *(uint4*)&Al[r0 * 40 + g0 * 8] = *(const uint4*)(Alo + a0);
      *(uint4*)&Al[r1 * 40 + g1 * 8] = *(const uint4*)(Alo + a1);
      *(uint4*)&Bh[r0 * 40 + g0 * 8] = *(const uint4*)(Bhi + b0);
      *(uint4*)&Bh[r1 * 40 + g1 * 8] = *(const uint4*)(Bhi + b1);
      *(uint4*)&Bl[r0 * 40 + g0 * 8] = *(const uint4*)(Blo + b0);
      *(uint4*)&Bl[r1 * 40 + g1 * 8] = *(const uint4*)(Blo + b1);
    }
    __syncthreads();
    short8 ah[4], al[4], bh[4], bl[4];
#pragma unroll
    for (int f = 0; f < 4; ++f) {
      ah[f] = *(const short8*)&Ah[(wm + f * 16 + l15) * 40 + l4 * 8];
      al[f] = *(const short8*)&Al[(wm + f * 16 + l15) * 40 + l4 * 8];
      bh[f] = *(const short8*)&Bh[(wn + f * 16 + l15) * 40 + l4 * 8];
      bl[f] = *(const short8*)&Bl[(wn + f * 16 + l15) * 40 + l4 * 8];
    }
#pragma unroll
    for (int mf = 0; mf < 4; ++mf)
#pragma unroll
      for (int nf = 0; nf < 4; ++nf) {
        acc[mf][nf] = __builtin_amdgcn_mfma_f32_16x16x32_bf16(ah[mf], bh[nf], acc[mf][nf], 0, 0, 0);
        acc[mf][nf] = __builtin_amdgcn_mfma_f32_16x16x32_bf16(ah[mf], bl[nf], acc[mf][nf], 0, 0, 0);
        acc[mf][nf] = __builtin_amdgcn_mfma_f32_16x16x32_bf16(al[mf], bh[nf], acc[mf][nf], 0, 0, 0);
      }
  }
  // epilogue: C/D col = lane&15, row = (lane>>4)*4 + j
#pragma unroll
  for (int mf = 0; mf < 4; ++mf)
#pragma unroll
    for (int nf = 0; nf < 4; ++nf)
#pragma unroll
      for (int j = 0; j < 4; ++j) {
        const int gm = m0 + wm + mf * 16 + l4 * 4 + j;
        const int gn = n0 + wn + nf * 16 + l15;
        float z = acc[mf][nf][j];
        if (SILU) z = z / (1.0f + expf(-z));
        if (OSPLIT) {
          unsigned h = bf16rne(z);
          float hf = __uint_as_float(h << 16);
          unsigned l = bf16rne(z - hf);
          Chi[(size_t)gm * N + gn] = (unsigned short)h;
          Clo[(size_t)gm * N + gn] = (unsigned short)l;
        } else {
          Cf[(size_t)gm * N + gn] = z;
        }
      }
}

// ---------------- top-k + softmax + code gather ----------------------------
// Wave-per-token, all-register bitonic top-32 via cross-lane shuffles.
// Sort key (u64): bits 16..47 = monotone-mapped fp32 (lossless), bits 0..15 =
// (1023 - idx). Larger key = higher value, ties by LOWEST index — exactly
// jax.lax.top_k semantics on fp32 values.
__device__ inline unsigned int fmap32(float f) {
  unsigned int u = __float_as_uint(f);
  return (u >> 31) ? ~u : (u | 0x80000000u);
}
__device__ inline float funmap32(unsigned int m) {
  return __uint_as_float((m & 0x80000000u) ? (m ^ 0x80000000u) : ~m);
}
__device__ inline u64 pack_key(float f, int e) {
  return ((u64)fmap32(f) << 16) | (u64)(1023 - e);
}
__device__ inline u64 shflx64(u64 v, int mask) {
  return __shfl_xor(v, mask, 64);
}
__device__ inline void cmpex(u64& x, u64 p, bool takeMax) {
  if ((x < p) == takeMax) x = p;
}

template<int NR>
__device__ inline void sort32_desc(u64* k, int l5) {
#pragma unroll 1
  for (int size = 2; size <= 32; size <<= 1) {
#pragma unroll 1
    for (int stride = size >> 1; stride > 0; stride >>= 1) {
      const bool takeMax = (((l5 & size) == 0) == ((l5 & stride) == 0));
#pragma unroll
      for (int r = 0; r < NR; ++r) {
        u64 p = shflx64(k[r], stride);
        cmpex(k[r], p, takeMax);
      }
    }
  }
}

template<int NR>
__device__ inline void bmerge32_desc(u64* k, int l5) {
#pragma unroll 1
  for (int stride = 16; stride > 0; stride >>= 1) {
    const bool takeMax = ((l5 & stride) == 0);
#pragma unroll
    for (int r = 0; r < NR; ++r) {
      u64 p = shflx64(k[r], stride);
      cmpex(k[r], p, takeMax);
    }
  }
}

template<int NR>
__device__ inline void halfmerge(u64* k, int l5) {
#pragma unroll
  for (int r = 0; r < NR; ++r) {
    u64 p = shflx64(k[r], 63);
    if (k[r] < p) k[r] = p;
  }
  bmerge32_desc<NR>(k, l5);
}

__device__ inline u64 merge2(u64 x, u64 y, int l5) {
  u64 p = shflx64(y, 31);
  if (x < p) x = p;
  bmerge32_desc<1>(&x, l5);
  return x;
}

__device__ inline u64 top32_of_1024(u64 k[16], int l5) {
  sort32_desc<16>(k, l5);
  halfmerge<16>(k, l5);
#pragma unroll
  for (int r = 0; r < 8; ++r) k[r] = merge2(k[2 * r], k[2 * r + 1], l5);
#pragma unroll
  for (int r = 0; r < 4; ++r) k[r] = merge2(k[2 * r], k[2 * r + 1], l5);
#pragma unroll
  for (int r = 0; r < 2; ++r) k[r] = merge2(k[2 * r], k[2 * r + 1], l5);
  return merge2(k[0], k[1], l5);
}

// Candidate-prune: top-32 of {ta[i]+tb[j]} (desc-sorted inputs) lies in the
// staircase (i+1)*(j+1) <= 32; dominated slots lose ties by position too.
// 119 real slots + 9 pad sentinels (0xFFFF -> key 0).
__device__ const unsigned short cand_tab[128] = {
    0,  1,  2,  3,  4,  5,  6,  7,  8,  9, 10, 11, 12, 13, 14, 15,
   16, 17, 18, 19, 20, 21, 22, 23, 24, 25, 26, 27, 28, 29, 30, 31,
   32, 33, 34, 35, 36, 37, 38, 39, 40, 41, 42, 43, 44, 45, 46, 47,
   64, 65, 66, 67, 68, 69, 70, 71, 72, 73,
   96, 97, 98, 99,100,101,102,103,
  128,129,130,131,132,133,
  160,161,162,163,164,
  192,193,194,195,
  224,225,226,227,
  256,257,258,
  288,289,290,
  320,321, 352,353, 384,385, 416,417, 448,449, 480,481,
  512,544,576,608,640,672,704,736,768,800,832,864,896,928,960,992,
  0xFFFF,0xFFFF,0xFFFF,0xFFFF,0xFFFF,0xFFFF,0xFFFF,0xFFFF,0xFFFF
};

__global__ __launch_bounds__(256) void topk_mix(
    const float* __restrict__ scores,    // [NTOK][2048]
    const float* __restrict__ codes,     // [NSUB*NSUB][CODED]
    unsigned short* __restrict__ mixedhi,// [NTOK][CODED] bf16 hi
    unsigned short* __restrict__ mixedlo)// [NTOK][CODED] bf16 lo
{
  const int lane = threadIdx.x & 63;
  const int wid  = threadIdx.x >> 6;
  const int token = blockIdx.x * 4 + wid;
  const int l5 = lane & 31;
  const float* row = scores + (size_t)token * 2048;

  u64 k[16];

#pragma unroll
  for (int r4 = 0; r4 < 4; ++r4) {
    float4 v = *(const float4*)(row + r4 * 256 + 4 * lane);
    const int e = r4 * 256 + 4 * lane;
    k[4 * r4 + 0] = pack_key(v.x, e + 0);
    k[4 * r4 + 1] = pack_key(v.y, e + 1);
    k[4 * r4 + 2] = pack_key(v.z, e + 2);
    k[4 * r4 + 3] = pack_key(v.w, e + 3);
  }
  const u64 ka = top32_of_1024(k, l5);
  const float va = funmap32((unsigned int)(ka >> 16));
  const int   ia = 1023 - (int)(ka & 0xFFFFULL);

#pragma unroll
  for (int r4 = 0; r4 < 4; ++r4) {
    float4 v = *(const float4*)(row + 1024 + r4 * 256 + 4 * lane);
    const int e = r4 * 256 + 4 * lane;
    k[4 * r4 + 0] = pack_key(v.x, e + 0);
    k[4 * r4 + 1] = pack_key(v.y, e + 1);
    k[4 * r4 + 2] = pack_key(v.z, e + 2);
    k[4 * r4 + 3] = pack_key(v.w, e + 3);
  }
  const u64 kb = top32_of_1024(k, l5);
  const float vb = funmap32((unsigned int)(kb >> 16));
  const int   ib = 1023 - (int)(kb & 0xFFFFULL);

#pragma unroll
  for (int r = 0; r < 2; ++r) {
    const int p  = cand_tab[r * 64 + lane];
    const int pi = (p == 0xFFFF) ? 0 : p;
    const float ta = __shfl(va, pi >> 5, 64);
    const float tb = __shfl(vb, pi & 31, 64);
    k[r] = (p == 0xFFFF) ? 0ULL : pack_key(ta + tb, p);
  }
  sort32_desc<2>(k, l5);
  halfmerge<2>(k, l5);
  const u64 kc = merge2(k[0], k[1], l5);
  const float cs = funmap32((unsigned int)(kc >> 16));
  const int   ps = 1023 - (int)(kc & 0xFFFFULL);
  const int cidx = __shfl(ia, ps >> 5, 64) * NSUB + __shfl(ib, ps & 31, 64);

  const float lg  = cs / 22.627416997969522f;
  const float lg0 = __shfl(lg, 0, 64);
  const float ev  = expf(lg - lg0);
  float s = ev;
#pragma unroll
  for (int m = 1; m < 32; m <<= 1) s += __shfl_xor(s, m, 64);
  const float w = ev / s;

  float2 acc = make_float2(0.f, 0.f);
#pragma unroll 8
  for (int kk = 0; kk < 32; ++kk) {
    const int   idx = __shfl(cidx, kk, 64);
    const float wk  = __shfl(w,    kk, 64);
    const float2 cv = *(const float2*)(codes + (size_t)idx * CODED + 2 * lane);
    acc.x = fmaf(wk, cv.x, acc.x);
    acc.y = fmaf(wk, cv.y, acc.y);
  }
  // split-bf16 emit (feeds the MFMA GEMM4); little-endian pack of 2 ushort
  unsigned hx = bf16rne(acc.x);
  unsigned lx = bf16rne(acc.x - __uint_as_float(hx << 16));
  unsigned hy = bf16rne(acc.y);
  unsigned ly = bf16rne(acc.y - __uint_as_float(hy << 16));
  *(unsigned*)(mixedhi + (size_t)token * CODED + 2 * lane) = hx | (hy << 16);
  *(unsigned*)(mixedlo + (size_t)token * CODED + 2 * lane) = lx | (ly << 16);
}

extern "C" void kernel_launch(void* const* d_in, const int* in_sizes, int n_in,
                              void* d_out, int out_size, void* d_ws, size_t ws_size,
                              hipStream_t stream)
{
  const float* x     = (const float*)d_in[0];
  const float* Wq    = (const float*)d_in[1];
  const float* key_a = (const float*)d_in[2];
  const float* key_b = (const float*)d_in[3];
  const float* codes = (const float*)d_in[4];
  const float* W1    = (const float*)d_in[5];
  const float* W2    = (const float*)d_in[6];
  float* out = (float*)d_out;

  // ws layout (KB offsets), total 104.5 MB (<116 MB proven):
  // q f32 [0,16384) — dead after GEMM3, reused as h_hi
  // scores f32 [16384, 81920)
  // W1hi 81920(+256) W1lo 82176 W2hi 82432(+2048) W2lo 84480
  // mixedhi 86528(+2048) mixedlo 88576 h_lo 90624(+16384) -> 107008
  char* ws = (char*)d_ws;
  float* q      = (float*)(ws);
  float* scores = (float*)(ws + (size_t)16384 * 1024);
  unsigned short* W1hi = (unsigned short*)(ws + (size_t)81920 * 1024);
  unsigned short* W1lo = (unsigned short*)(ws + (size_t)82176 * 1024);
  unsigned short* W2hi = (unsigned short*)(ws + (size_t)82432 * 1024);
  unsigned short* W2lo = (unsigned short*)(ws + (size_t)84480 * 1024);
  unsigned short* mixedhi = (unsigned short*)(ws + (size_t)86528 * 1024);
  unsigned short* mixedlo = (unsigned short*)(ws + (size_t)88576 * 1024);
  unsigned short* h_hi = (unsigned short*)(ws);   // reuse q region (16 MB)
  unsigned short* h_lo = (unsigned short*)(ws + (size_t)90624 * 1024);

  // weight splits for the MFMA path (W1: 128K elems, W2: 1M elems)
  split_bf16<<<DIM * CODED / 256, 256, 0, stream>>>(W1, W1hi, W1lo, DIM * CODED);
  split_bf16<<<DIM * DIM  / 256, 256, 0, stream>>>(W2, W2hi, W2lo, DIM * DIM);

  // q = x @ Wq^T  (fp32, sequential-k accumulation — selection-critical)
  sgemm_nt<0><<<dim3(512 / 128, NTOK / 128), 256, 0, stream>>>(
      x, Wq, q, NTOK, 512, DIM, DIM, DIM, 512);
  // scores_a / scores_b (selection-critical, exact fp32)
  sgemm_nt<0><<<dim3(NSUB / 128, NTOK / 128), 256, 0, stream>>>(
      q, key_a, scores, NTOK, NSUB, KEYD, 512, KEYD, 2048);
  sgemm_nt<0><<<dim3(NSUB / 128, NTOK / 128), 256, 0, stream>>>(
      q + KEYD, key_b, scores + NSUB, NTOK, NSUB, KEYD, 512, KEYD, 2048);
  // top-k -> softmax -> code mix; emits mixed as split bf16
  topk_mix<<<NTOK / 4, 256, 0, stream>>>(scores, codes, mixedhi, mixedlo);
  // h = silu(mixed @ W1^T) via split-bf16 MFMA; emits h pre-split
  mgemm_nt<1, 1><<<dim3(DIM / 128, NTOK / 128), 256, 0, stream>>>(
      mixedhi, mixedlo, W1hi, W1lo, nullptr, h_hi, h_lo, NTOK, DIM, CODED);
  // out = h @ W2^T via split-bf16 MFMA (fp32 output)
  mgemm_nt<0, 0><<<dim3(DIM / 128, NTOK / 128), 256, 0, stream>>>(
      h_hi, h_lo, W2hi, W2lo, out, nullptr, nullptr, NTOK, DIM, DIM);
}